// Round 1
// baseline (509.873 us; speedup 1.0000x reference)
//
#include <hip/hip_runtime.h>
#include <cstdint>
#include <cstddef>

#define B_N   32768
#define C_N   1000
#define C_PAD 1024
#define D_N   256
#define K_N   16
#define ULB_N 50000
#define CAP   256

// output layout (floats): label[B], weight[B], topN[C*K], fidx[C*K], selected[ULB]
#define OFF_L 0
#define OFF_W 32768
#define OFF_T 65536
#define OFF_F 81536
#define OFF_S 97536

__device__ __forceinline__ unsigned ordf(float f) {
  unsigned u = __float_as_uint(f);
  return (u & 0x80000000u) ? ~u : (u | 0x80000000u);
}
__device__ __forceinline__ float iordf(unsigned h) {
  unsigned u = (h & 0x80000000u) ? (h & 0x7FFFFFFFu) : ~h;
  return __uint_as_float(u);
}

__global__ void k_init(unsigned long long* keys, float* s1, float* s2,
                       int* cnt, int* ctr, int* ovf, int* besti) {
  int i = blockIdx.x * blockDim.x + threadIdx.x;
  if (i < B_N)  keys[i] = 0ull;
  if (i < C_PAD) { s1[i] = 0.f; s2[i] = 0.f; cnt[i] = 0; ctr[i] = 0; ovf[i] = 0; }
  if (i < ULB_N) besti[i] = -1;
}

// normalize centroids; pad rows [1000,1024) with zeros
__global__ void k_cnorm(const float* __restrict__ cent, float* __restrict__ cn) {
  int c = blockIdx.x, t = threadIdx.x;  // block = 64 threads, one row
  if (c >= C_N) {
    float4 z = {0.f, 0.f, 0.f, 0.f};
    *reinterpret_cast<float4*>(&cn[(size_t)c * D_N + 4 * t]) = z;
    return;
  }
  float4 v = *reinterpret_cast<const float4*>(&cent[(size_t)c * D_N + 4 * t]);
  float ss = v.x * v.x; ss += v.y * v.y; ss += v.z * v.z; ss += v.w * v.w;
  #pragma unroll
  for (int mk = 1; mk < 64; mk <<= 1) ss += __shfl_xor(ss, mk, 64);
  float d = fmaxf(sqrtf(ss), 1e-8f);
  float4 o; o.x = v.x / d; o.y = v.y / d; o.z = v.z / d; o.w = v.w / d;
  *reinterpret_cast<float4*>(&cn[(size_t)c * D_N + 4 * t]) = o;
}

// per-sample norm divisor d = max(||x||, eps)
__global__ void k_dfeat(const float* __restrict__ feat, float* __restrict__ dfeat) {
  int r = blockIdx.x, t = threadIdx.x;  // block = 64
  float4 v = *reinterpret_cast<const float4*>(&feat[(size_t)r * D_N + 4 * t]);
  float ss = v.x * v.x; ss += v.y * v.y; ss += v.z * v.z; ss += v.w * v.w;
  #pragma unroll
  for (int mk = 1; mk < 64; mk <<= 1) ss += __shfl_xor(ss, mk, 64);
  if (t == 0) dfeat[r] = fmaxf(sqrtf(ss), 1e-8f);
}

// 128x128 tile fp32 GEMM (cos = fn @ cn^T) with fused row max/argmax via packed atomicMax.
__global__ __launch_bounds__(256) void k_gemm(const float* __restrict__ feat,
                                              const float* __restrict__ dfeat,
                                              const float* __restrict__ cn,
                                              unsigned long long* __restrict__ keys) {
  __shared__ __align__(16) float As[32][132];  // [k][m]
  __shared__ __align__(16) float Bs[32][132];  // [k][c]
  const int tid = threadIdx.x;
  const int bx = blockIdx.x;            // c tile 0..7 (c covers 0..1023, padded)
  const int by = blockIdx.y;            // m tile 0..255
  const int m0 = by * 128, c0 = bx * 128;
  const int tx = tid & 15, ty = tid >> 4;
  const int frow = tid >> 3;            // 0..31
  const int fk4 = tid & 7;              // 0..7

  float acc[8][8];
  #pragma unroll
  for (int i = 0; i < 8; ++i)
    #pragma unroll
    for (int j = 0; j < 8; ++j) acc[i][j] = 0.f;

  float dm[4];
  #pragma unroll
  for (int r = 0; r < 4; ++r) dm[r] = dfeat[m0 + frow + 32 * r];

  for (int kt = 0; kt < 8; ++kt) {
    const int kb = kt * 32;
    #pragma unroll
    for (int r = 0; r < 4; ++r) {
      int m = frow + 32 * r;
      float4 v = *reinterpret_cast<const float4*>(&feat[(size_t)(m0 + m) * D_N + kb + 4 * fk4]);
      float dd = dm[r];
      v.x /= dd; v.y /= dd; v.z /= dd; v.w /= dd;   // matches ref x/max(||x||,eps)
      As[4 * fk4 + 0][m] = v.x; As[4 * fk4 + 1][m] = v.y;
      As[4 * fk4 + 2][m] = v.z; As[4 * fk4 + 3][m] = v.w;
    }
    #pragma unroll
    for (int r = 0; r < 4; ++r) {
      int c = frow + 32 * r;
      float4 v = *reinterpret_cast<const float4*>(&cn[(size_t)(c0 + c) * D_N + kb + 4 * fk4]);
      Bs[4 * fk4 + 0][c] = v.x; Bs[4 * fk4 + 1][c] = v.y;
      Bs[4 * fk4 + 2][c] = v.z; Bs[4 * fk4 + 3][c] = v.w;
    }
    __syncthreads();
    #pragma unroll
    for (int kk = 0; kk < 32; ++kk) {
      float4 a0 = *reinterpret_cast<const float4*>(&As[kk][8 * ty]);
      float4 a1 = *reinterpret_cast<const float4*>(&As[kk][8 * ty + 4]);
      float4 b0 = *reinterpret_cast<const float4*>(&Bs[kk][8 * tx]);
      float4 b1 = *reinterpret_cast<const float4*>(&Bs[kk][8 * tx + 4]);
      float av[8] = {a0.x, a0.y, a0.z, a0.w, a1.x, a1.y, a1.z, a1.w};
      float bv[8] = {b0.x, b0.y, b0.z, b0.w, b1.x, b1.y, b1.z, b1.w};
      #pragma unroll
      for (int i = 0; i < 8; ++i)
        #pragma unroll
        for (int j = 0; j < 8; ++j)
          acc[i][j] = fmaf(av[i], bv[j], acc[i][j]);
    }
    __syncthreads();
  }

  // fused per-row max/argmax (first-max tie-break via ascending c + packed key)
  #pragma unroll
  for (int i = 0; i < 8; ++i) {
    float bvv = -INFINITY; int bc = 0x7FFFFFFF;
    #pragma unroll
    for (int j = 0; j < 8; ++j) {
      int cg = c0 + 8 * tx + j;
      float v = acc[i][j];
      if (cg < C_N && v > bvv) { bvv = v; bc = cg; }
    }
    #pragma unroll
    for (int mk = 1; mk < 16; mk <<= 1) {
      float ov = __shfl_xor(bvv, mk, 64);
      int oc = __shfl_xor(bc, mk, 64);
      if (ov > bvv || (ov == bvv && oc < bc)) { bvv = ov; bc = oc; }
    }
    if (tx == 0) {
      unsigned long long kkey =
          (((unsigned long long)ordf(bvv)) << 32) |
          (unsigned long long)(0xFFFFFFFFu - (unsigned)bc);
      atomicMax(&keys[m0 + 8 * ty + i], kkey);
    }
  }
}

// row softmax max = 1/sum(exp(x - max))
__global__ __launch_bounds__(256) void k_scores(const float* __restrict__ pred,
                                                float* __restrict__ scores) {
  __shared__ float red[8];
  int r = blockIdx.x, t = threadIdx.x;
  const float* row = pred + (size_t)r * C_N;
  float x0 = row[t];
  float x1 = row[256 + t];
  float x2 = row[512 + t];
  bool v3 = (768 + t) < C_N;
  float x3 = v3 ? row[768 + t] : -INFINITY;
  float m = fmaxf(fmaxf(x0, x1), fmaxf(x2, x3));
  #pragma unroll
  for (int mk = 1; mk < 64; mk <<= 1) m = fmaxf(m, __shfl_xor(m, mk, 64));
  int wid = t >> 6, lane = t & 63;
  if (lane == 0) red[wid] = m;
  __syncthreads();
  m = fmaxf(fmaxf(red[0], red[1]), fmaxf(red[2], red[3]));
  float s = expf(x0 - m) + expf(x1 - m) + expf(x2 - m) + (v3 ? expf(x3 - m) : 0.f);
  #pragma unroll
  for (int mk = 1; mk < 64; mk <<= 1) s += __shfl_xor(s, mk, 64);
  __syncthreads();
  if (lane == 0) red[4 + wid] = s;
  __syncthreads();
  if (t == 0) {
    float S = ((red[4] + red[5]) + red[6]) + red[7];
    scores[r] = 1.0f / S;
  }
}

__global__ void k_post(const unsigned long long* __restrict__ keys, const int* __restrict__ ui,
                       int* __restrict__ labels, float* __restrict__ cosf_,
                       float* __restrict__ s1, float* __restrict__ s2, int* __restrict__ cnt,
                       int* __restrict__ ctr, int* __restrict__ ovf, int* __restrict__ lists,
                       int* __restrict__ besti, float* __restrict__ out) {
  int b = blockIdx.x * blockDim.x + threadIdx.x;
  if (b >= B_N) return;
  unsigned long long k = keys[b];
  int c = (int)(0xFFFFFFFFu - (unsigned)k);
  float f = iordf((unsigned)(k >> 32));
  labels[b] = c;
  cosf_[b] = f;
  out[OFF_L + b] = (float)c;
  atomicAdd(&s1[c], f);
  atomicAdd(&s2[c], f * f);
  atomicAdd(&cnt[c], 1);
  int pos = atomicAdd(&ctr[c], 1);
  if (pos < CAP) lists[c * CAP + pos] = b;
  else ovf[c] = 1;
  atomicMax(&besti[ui[b]], b);   // last-write-wins => largest sample index
}

__global__ void k_weight(const int* __restrict__ labels, const float* __restrict__ cosf_,
                         const float* __restrict__ s1, const float* __restrict__ s2,
                         const int* __restrict__ cnt, float* __restrict__ out) {
  int b = blockIdx.x * blockDim.x + threadIdx.x;
  if (b >= B_N) return;
  int l = labels[b];
  float n = (float)cnt[l];
  float m = s1[l] / fmaxf(n, 1.0f);
  float var = (s2[l] - n * m * m) / fmaxf(n - 1.0f, 1.0f);
  float sd = sqrtf(fmaxf(var, 0.0f) + 1e-12f);
  float cf = cosf_[b];
  float w = 1.0f;
  if (cf < m) {
    float z = (cf - m) / sd;
    const float inv = 1.0f / sqrtf(6.283185307179586f);
    w = expf(-0.5f * (z * z)) * inv / sd;
  }
  out[OFF_W + b] = w;
}

// per-class ordered replay of the streaming top-K insertion
__global__ void k_scan(const float* __restrict__ ptn, const float* __restrict__ scores,
                       const int* __restrict__ labels, const int* __restrict__ ui,
                       const int* __restrict__ lists, const int* __restrict__ ctr,
                       const int* __restrict__ ovf, float* __restrict__ out) {
  int c = blockIdx.x * blockDim.x + threadIdx.x;
  if (c >= C_N) return;
  float tv[K_N]; int fi[K_N];
  #pragma unroll
  for (int j = 0; j < K_N; ++j) { tv[j] = ptn[c * K_N + j]; fi[j] = -1; }

  auto ins = [&](float s, int u) {
    float mv = tv[0]; int mi = 0;
    #pragma unroll
    for (int j = 1; j < K_N; ++j) { if (tv[j] < mv) { mv = tv[j]; mi = j; } }  // first-min
    if (s > mv) {
      #pragma unroll
      for (int j = 0; j < K_N; ++j) { if (j == mi) { tv[j] = s; fi[j] = u; } }
    }
  };

  if (!ovf[c]) {
    int n = ctr[c];
    int idx[CAP];
    for (int t = 0; t < n; ++t) idx[t] = lists[c * CAP + t];
    for (int t = 1; t < n; ++t) {          // insertion sort ascending (restore scan order)
      int v = idx[t]; int u = t - 1;
      while (u >= 0 && idx[u] > v) { idx[u + 1] = idx[u]; --u; }
      idx[u + 1] = v;
    }
    for (int t = 0; t < n; ++t) {
      int b = idx[t];
      ins(scores[b], ui[b]);
    }
  } else {
    for (int b = 0; b < B_N; ++b) {
      if (labels[b] == c) ins(scores[b], ui[b]);
    }
  }

  #pragma unroll
  for (int j = 0; j < K_N; ++j) {
    out[OFF_T + c * K_N + j] = tv[j];
    out[OFF_F + c * K_N + j] = (float)fi[j];
  }
}

__global__ void k_sel(const int* __restrict__ besti, const int* __restrict__ labels,
                      float* __restrict__ out) {
  int p = blockIdx.x * blockDim.x + threadIdx.x;
  if (p >= ULB_N) return;
  int bi = besti[p];
  out[OFF_S + p] = (bi < 0) ? -1.0f : (float)labels[bi];
}

extern "C" void kernel_launch(void* const* d_in, const int* in_sizes, int n_in,
                              void* d_out, int out_size, void* d_ws, size_t ws_size,
                              hipStream_t stream) {
  const float* feat = (const float*)d_in[0];
  const float* pred = (const float*)d_in[1];
  const float* cent = (const float*)d_in[2];
  const float* ptn  = (const float*)d_in[3];
  const int*   ui   = (const int*)d_in[4];
  float* out = (float*)d_out;
  char* ws = (char*)d_ws;

  float* cn                 = (float*)(ws + 0);          // 1,048,576 B
  float* dfeat              = (float*)(ws + 1048576);    //   131,072
  unsigned long long* keys  = (unsigned long long*)(ws + 1179648);  // 262,144
  int*   labels             = (int*)  (ws + 1441792);    //   131,072
  float* scores             = (float*)(ws + 1572864);    //   131,072
  float* cosf_              = (float*)(ws + 1703936);    //   131,072
  float* s1                 = (float*)(ws + 1835008);    //     4,096
  float* s2                 = (float*)(ws + 1839104);    //     4,096
  int*   cnt                = (int*)  (ws + 1843200);    //     4,096
  int*   ctr                = (int*)  (ws + 1847296);    //     4,096
  int*   ovf                = (int*)  (ws + 1851392);    //     4,096
  int*   besti              = (int*)  (ws + 1855488);    //   200,704
  int*   lists              = (int*)  (ws + 2056192);    // 1,024,000  (end ~2.94 MB)

  k_init  <<<196, 256, 0, stream>>>(keys, s1, s2, cnt, ctr, ovf, besti);
  k_cnorm <<<C_PAD, 64, 0, stream>>>(cent, cn);
  k_dfeat <<<B_N, 64, 0, stream>>>(feat, dfeat);
  k_gemm  <<<dim3(8, 256), 256, 0, stream>>>(feat, dfeat, cn, keys);
  k_scores<<<B_N, 256, 0, stream>>>(pred, scores);
  k_post  <<<B_N / 256, 256, 0, stream>>>(keys, ui, labels, cosf_, s1, s2, cnt, ctr, ovf, lists, besti, out);
  k_weight<<<B_N / 256, 256, 0, stream>>>(labels, cosf_, s1, s2, cnt, out);
  k_scan  <<<8, 128, 0, stream>>>(ptn, scores, labels, ui, lists, ctr, ovf, out);
  k_sel   <<<(ULB_N + 255) / 256, 256, 0, stream>>>(besti, labels, out);
}

// Round 2
// 303.814 us; speedup vs baseline: 1.6782x; 1.6782x over previous
//
#include <hip/hip_runtime.h>
#include <cstdint>
#include <cstddef>

#define B_N   32768
#define C_N   1000
#define C_PAD 1024
#define D_N   256
#define K_N   16
#define ULB_N 50000
#define NCHUNK 128           // B_N / 256
#define CAP_L 128            // per-class sorted-list capacity

// output layout (floats): label[B], weight[B], topN[C*K], fidx[C*K], selected[ULB]
#define OFF_L 0
#define OFF_W 32768
#define OFF_T 65536
#define OFF_F 81536
#define OFF_S 97536

__device__ __forceinline__ unsigned ordf(float f) {
  unsigned u = __float_as_uint(f);
  return (u & 0x80000000u) ? ~u : (u | 0x80000000u);
}
__device__ __forceinline__ float iordf(unsigned h) {
  unsigned u = (h & 0x80000000u) ? (h & 0x7FFFFFFFu) : ~h;
  return __uint_as_float(u);
}

__global__ void k_init(unsigned long long* keys, float* s1, float* s2,
                       int* cnt, int* besti) {
  int i = blockIdx.x * blockDim.x + threadIdx.x;
  if (i < B_N)  keys[i] = 0ull;
  if (i < C_PAD) { s1[i] = 0.f; s2[i] = 0.f; cnt[i] = 0; }
  if (i < ULB_N) besti[i] = -1;
}

// normalize centroids; pad rows [1000,1024) with zeros
__global__ void k_cnorm(const float* __restrict__ cent, float* __restrict__ cn) {
  int c = blockIdx.x, t = threadIdx.x;  // block = 64 threads, one row
  if (c >= C_N) {
    float4 z = {0.f, 0.f, 0.f, 0.f};
    *reinterpret_cast<float4*>(&cn[(size_t)c * D_N + 4 * t]) = z;
    return;
  }
  float4 v = *reinterpret_cast<const float4*>(&cent[(size_t)c * D_N + 4 * t]);
  float ss = v.x * v.x; ss += v.y * v.y; ss += v.z * v.z; ss += v.w * v.w;
  #pragma unroll
  for (int mk = 1; mk < 64; mk <<= 1) ss += __shfl_xor(ss, mk, 64);
  float d = fmaxf(sqrtf(ss), 1e-8f);
  float4 o; o.x = v.x / d; o.y = v.y / d; o.z = v.z / d; o.w = v.w / d;
  *reinterpret_cast<float4*>(&cn[(size_t)c * D_N + 4 * t]) = o;
}

// per-sample norm divisor d = max(||x||, eps)
__global__ void k_dfeat(const float* __restrict__ feat, float* __restrict__ dfeat) {
  int r = blockIdx.x, t = threadIdx.x;  // block = 64
  float4 v = *reinterpret_cast<const float4*>(&feat[(size_t)r * D_N + 4 * t]);
  float ss = v.x * v.x; ss += v.y * v.y; ss += v.z * v.z; ss += v.w * v.w;
  #pragma unroll
  for (int mk = 1; mk < 64; mk <<= 1) ss += __shfl_xor(ss, mk, 64);
  if (t == 0) dfeat[r] = fmaxf(sqrtf(ss), 1e-8f);
}

// 128x128 tile fp32 GEMM (cos = fn @ cn^T) with fused row max/argmax via packed atomicMax.
__global__ __launch_bounds__(256) void k_gemm(const float* __restrict__ feat,
                                              const float* __restrict__ dfeat,
                                              const float* __restrict__ cn,
                                              unsigned long long* __restrict__ keys) {
  __shared__ __align__(16) float As[32][132];  // [k][m]
  __shared__ __align__(16) float Bs[32][132];  // [k][c]
  const int tid = threadIdx.x;
  const int bx = blockIdx.x;            // c tile 0..7 (c covers 0..1023, padded)
  const int by = blockIdx.y;            // m tile 0..255
  const int m0 = by * 128, c0 = bx * 128;
  const int tx = tid & 15, ty = tid >> 4;
  const int frow = tid >> 3;            // 0..31
  const int fk4 = tid & 7;              // 0..7

  float acc[8][8];
  #pragma unroll
  for (int i = 0; i < 8; ++i)
    #pragma unroll
    for (int j = 0; j < 8; ++j) acc[i][j] = 0.f;

  float dm[4];
  #pragma unroll
  for (int r = 0; r < 4; ++r) dm[r] = dfeat[m0 + frow + 32 * r];

  for (int kt = 0; kt < 8; ++kt) {
    const int kb = kt * 32;
    #pragma unroll
    for (int r = 0; r < 4; ++r) {
      int m = frow + 32 * r;
      float4 v = *reinterpret_cast<const float4*>(&feat[(size_t)(m0 + m) * D_N + kb + 4 * fk4]);
      float dd = dm[r];
      v.x /= dd; v.y /= dd; v.z /= dd; v.w /= dd;   // matches ref x/max(||x||,eps)
      As[4 * fk4 + 0][m] = v.x; As[4 * fk4 + 1][m] = v.y;
      As[4 * fk4 + 2][m] = v.z; As[4 * fk4 + 3][m] = v.w;
    }
    #pragma unroll
    for (int r = 0; r < 4; ++r) {
      int c = frow + 32 * r;
      float4 v = *reinterpret_cast<const float4*>(&cn[(size_t)(c0 + c) * D_N + kb + 4 * fk4]);
      Bs[4 * fk4 + 0][c] = v.x; Bs[4 * fk4 + 1][c] = v.y;
      Bs[4 * fk4 + 2][c] = v.z; Bs[4 * fk4 + 3][c] = v.w;
    }
    __syncthreads();
    #pragma unroll
    for (int kk = 0; kk < 32; ++kk) {
      float4 a0 = *reinterpret_cast<const float4*>(&As[kk][8 * ty]);
      float4 a1 = *reinterpret_cast<const float4*>(&As[kk][8 * ty + 4]);
      float4 b0 = *reinterpret_cast<const float4*>(&Bs[kk][8 * tx]);
      float4 b1 = *reinterpret_cast<const float4*>(&Bs[kk][8 * tx + 4]);
      float av[8] = {a0.x, a0.y, a0.z, a0.w, a1.x, a1.y, a1.z, a1.w};
      float bv[8] = {b0.x, b0.y, b0.z, b0.w, b1.x, b1.y, b1.z, b1.w};
      #pragma unroll
      for (int i = 0; i < 8; ++i)
        #pragma unroll
        for (int j = 0; j < 8; ++j)
          acc[i][j] = fmaf(av[i], bv[j], acc[i][j]);
    }
    __syncthreads();
  }

  // fused per-row max/argmax (first-max tie-break via ascending c + packed key)
  #pragma unroll
  for (int i = 0; i < 8; ++i) {
    float bvv = -INFINITY; int bc = 0x7FFFFFFF;
    #pragma unroll
    for (int j = 0; j < 8; ++j) {
      int cg = c0 + 8 * tx + j;
      float v = acc[i][j];
      if (cg < C_N && v > bvv) { bvv = v; bc = cg; }
    }
    #pragma unroll
    for (int mk = 1; mk < 16; mk <<= 1) {
      float ov = __shfl_xor(bvv, mk, 64);
      int oc = __shfl_xor(bc, mk, 64);
      if (ov > bvv || (ov == bvv && oc < bc)) { bvv = ov; bc = oc; }
    }
    if (tx == 0) {
      unsigned long long kkey =
          (((unsigned long long)ordf(bvv)) << 32) |
          (unsigned long long)(0xFFFFFFFFu - (unsigned)bc);
      atomicMax(&keys[m0 + 8 * ty + i], kkey);
    }
  }
}

// row softmax max = 1/sum(exp(x - max))
__global__ __launch_bounds__(256) void k_scores(const float* __restrict__ pred,
                                                float* __restrict__ scores) {
  __shared__ float red[8];
  int r = blockIdx.x, t = threadIdx.x;
  const float* row = pred + (size_t)r * C_N;
  float x0 = row[t];
  float x1 = row[256 + t];
  float x2 = row[512 + t];
  bool v3 = (768 + t) < C_N;
  float x3 = v3 ? row[768 + t] : -INFINITY;
  float m = fmaxf(fmaxf(x0, x1), fmaxf(x2, x3));
  #pragma unroll
  for (int mk = 1; mk < 64; mk <<= 1) m = fmaxf(m, __shfl_xor(m, mk, 64));
  int wid = t >> 6, lane = t & 63;
  if (lane == 0) red[wid] = m;
  __syncthreads();
  m = fmaxf(fmaxf(red[0], red[1]), fmaxf(red[2], red[3]));
  float s = expf(x0 - m) + expf(x1 - m) + expf(x2 - m) + (v3 ? expf(x3 - m) : 0.f);
  #pragma unroll
  for (int mk = 1; mk < 64; mk <<= 1) s += __shfl_xor(s, mk, 64);
  __syncthreads();
  if (lane == 0) red[4 + wid] = s;
  __syncthreads();
  if (t == 0) {
    float S = ((red[4] + red[5]) + red[6]) + red[7];
    scores[r] = 1.0f / S;
  }
}

__global__ void k_post(const unsigned long long* __restrict__ keys, const int* __restrict__ ui,
                       int* __restrict__ labels, float* __restrict__ cosf_,
                       float* __restrict__ s1, float* __restrict__ s2, int* __restrict__ cnt,
                       int* __restrict__ besti, float* __restrict__ out) {
  int b = blockIdx.x * blockDim.x + threadIdx.x;
  if (b >= B_N) return;
  unsigned long long k = keys[b];
  int c = (int)(0xFFFFFFFFu - (unsigned)k);
  float f = iordf((unsigned)(k >> 32));
  labels[b] = c;
  cosf_[b] = f;
  out[OFF_L + b] = (float)c;
  atomicAdd(&s1[c], f);
  atomicAdd(&s2[c], f * f);
  atomicAdd(&cnt[c], 1);
  atomicMax(&besti[ui[b]], b);   // last-write-wins => largest sample index
}

// per-chunk class histogram + within-chunk stable rank (chunk = 256 samples)
__global__ __launch_bounds__(256) void k_hist_rank(const int* __restrict__ labels,
                                                   unsigned short* __restrict__ lrank,
                                                   unsigned short* __restrict__ hist) {
  __shared__ int lab[256];
  __shared__ unsigned histl[C_PAD];
  int chunk = blockIdx.x, t = threadIdx.x;
  int b = chunk * 256 + t;
  #pragma unroll
  for (int r = 0; r < 4; ++r) histl[t + 256 * r] = 0;
  int c = labels[b];
  lab[t] = c;
  __syncthreads();
  atomicAdd(&histl[c], 1u);
  unsigned rk = 0;
  for (int j = 0; j < t; ++j) rk += (lab[j] == c);
  lrank[b] = (unsigned short)rk;
  __syncthreads();
  #pragma unroll
  for (int r = 0; r < 4; ++r)
    hist[chunk * C_PAD + t + 256 * r] = (unsigned short)histl[t + 256 * r];
}

// per-class exclusive prefix over chunks; also total count per class
__global__ void k_prefix(const unsigned short* __restrict__ hist,
                         unsigned short* __restrict__ base,
                         int* __restrict__ class_n) {
  int c = blockIdx.x * 64 + threadIdx.x;   // 16 blocks x 64
  unsigned run = 0;
  for (int t = 0; t < NCHUNK; ++t) {
    unsigned h = hist[t * C_PAD + c];
    base[t * C_PAD + c] = (unsigned short)run;
    run += h;
  }
  class_n[c] = (int)run;
}

// scatter score/ui into per-class lists, pre-sorted by sample index
__global__ __launch_bounds__(256) void k_scatter(const int* __restrict__ labels,
                                                 const unsigned short* __restrict__ lrank,
                                                 const unsigned short* __restrict__ base,
                                                 const float* __restrict__ scores,
                                                 const int* __restrict__ ui,
                                                 float* __restrict__ lists_s,
                                                 int* __restrict__ lists_u) {
  int b = blockIdx.x * blockDim.x + threadIdx.x;
  if (b >= B_N) return;
  int c = labels[b];
  int chunk = b >> 8;
  int pos = (int)base[chunk * C_PAD + c] + (int)lrank[b];
  if (pos < CAP_L) {
    lists_s[c * CAP_L + pos] = scores[b];
    lists_u[c * CAP_L + pos] = ui[b];
  }
}

__global__ void k_weight(const int* __restrict__ labels, const float* __restrict__ cosf_,
                         const float* __restrict__ s1, const float* __restrict__ s2,
                         const int* __restrict__ cnt, float* __restrict__ out) {
  int b = blockIdx.x * blockDim.x + threadIdx.x;
  if (b >= B_N) return;
  int l = labels[b];
  float n = (float)cnt[l];
  float m = s1[l] / fmaxf(n, 1.0f);
  float var = (s2[l] - n * m * m) / fmaxf(n - 1.0f, 1.0f);
  float sd = sqrtf(fmaxf(var, 0.0f) + 1e-12f);
  float cf = cosf_[b];
  float w = 1.0f;
  if (cf < m) {
    float z = (cf - m) / sd;
    const float inv = 1.0f / sqrtf(6.283185307179586f);
    w = expf(-0.5f * (z * z)) * inv / sd;
  }
  out[OFF_W + b] = w;
}

// one wave per class: parallel 64-wide gather of the pre-sorted list,
// serial top-16 replay via shfl broadcast (all lanes replicate state).
__global__ __launch_bounds__(256) void k_replay(const float* __restrict__ ptn,
                                                const float* __restrict__ lists_s,
                                                const int* __restrict__ lists_u,
                                                const int* __restrict__ class_n,
                                                const int* __restrict__ labels,
                                                const float* __restrict__ scores,
                                                const int* __restrict__ ui,
                                                float* __restrict__ out) {
  int c = blockIdx.x * 4 + (threadIdx.x >> 6);
  int lane = threadIdx.x & 63;
  if (c >= C_N) return;

  float tv[K_N]; int fi[K_N];
  #pragma unroll
  for (int j = 0; j < K_N; ++j) { tv[j] = ptn[c * K_N + j]; fi[j] = -1; }

  auto ins = [&](float s, int u) {
    float mv = tv[0]; int mi = 0;
    #pragma unroll
    for (int j = 1; j < K_N; ++j) { if (tv[j] < mv) { mv = tv[j]; mi = j; } }  // first-min
    if (s > mv) {
      #pragma unroll
      for (int j = 0; j < K_N; ++j) { if (j == mi) { tv[j] = s; fi[j] = u; } }
    }
  };

  int n = class_n[c];
  if (n <= CAP_L) {
    for (int t0 = 0; t0 < n; t0 += 64) {
      float s = 0.f; int u = 0;
      int idx = t0 + lane;
      if (idx < n) { s = lists_s[c * CAP_L + idx]; u = lists_u[c * CAP_L + idx]; }
      int lim = min(64, n - t0);
      for (int t = 0; t < lim; ++t) {
        float ss = __shfl(s, t, 64);
        int uu = __shfl(u, t, 64);
        ins(ss, uu);
      }
    }
  } else {
    // cooperative fallback (practically unreachable): scan all samples in order
    for (int t0 = 0; t0 < B_N; t0 += 64) {
      int lb = labels[t0 + lane];
      unsigned long long match = __ballot(lb == c);
      while (match) {
        int t = __ffsll((long long)match) - 1;
        match &= match - 1;
        int b = t0 + t;
        ins(scores[b], ui[b]);
      }
    }
  }

  if (lane == 0) {
    #pragma unroll
    for (int j = 0; j < K_N; ++j) {
      out[OFF_T + c * K_N + j] = tv[j];
      out[OFF_F + c * K_N + j] = (float)fi[j];
    }
  }
}

__global__ void k_sel(const int* __restrict__ besti, const int* __restrict__ labels,
                      float* __restrict__ out) {
  int p = blockIdx.x * blockDim.x + threadIdx.x;
  if (p >= ULB_N) return;
  int bi = besti[p];
  out[OFF_S + p] = (bi < 0) ? -1.0f : (float)labels[bi];
}

extern "C" void kernel_launch(void* const* d_in, const int* in_sizes, int n_in,
                              void* d_out, int out_size, void* d_ws, size_t ws_size,
                              hipStream_t stream) {
  const float* feat = (const float*)d_in[0];
  const float* pred = (const float*)d_in[1];
  const float* cent = (const float*)d_in[2];
  const float* ptn  = (const float*)d_in[3];
  const int*   ui   = (const int*)d_in[4];
  float* out = (float*)d_out;
  char* ws = (char*)d_ws;

  size_t o = 0;
  auto alloc = [&](size_t bytes) { void* p = ws + o; o += (bytes + 255) & ~size_t(255); return p; };
  float* cn                 = (float*)alloc(C_PAD * D_N * 4);        // 1 MB
  float* dfeat              = (float*)alloc(B_N * 4);
  unsigned long long* keys  = (unsigned long long*)alloc(B_N * 8);
  int*   labels             = (int*)  alloc(B_N * 4);
  float* scores             = (float*)alloc(B_N * 4);
  float* cosf_              = (float*)alloc(B_N * 4);
  float* s1                 = (float*)alloc(C_PAD * 4);
  float* s2                 = (float*)alloc(C_PAD * 4);
  int*   cnt                = (int*)  alloc(C_PAD * 4);
  int*   besti              = (int*)  alloc(ULB_N * 4);
  unsigned short* lrank     = (unsigned short*)alloc(B_N * 2);
  unsigned short* hist      = (unsigned short*)alloc(NCHUNK * C_PAD * 2);
  unsigned short* base      = (unsigned short*)alloc(NCHUNK * C_PAD * 2);
  int*   class_n            = (int*)  alloc(C_PAD * 4);
  float* lists_s            = (float*)alloc(C_N * CAP_L * 4);
  int*   lists_u            = (int*)  alloc(C_N * CAP_L * 4);

  k_init     <<<196, 256, 0, stream>>>(keys, s1, s2, cnt, besti);
  k_cnorm    <<<C_PAD, 64, 0, stream>>>(cent, cn);
  k_dfeat    <<<B_N, 64, 0, stream>>>(feat, dfeat);
  k_gemm     <<<dim3(8, 256), 256, 0, stream>>>(feat, dfeat, cn, keys);
  k_scores   <<<B_N, 256, 0, stream>>>(pred, scores);
  k_post     <<<B_N / 256, 256, 0, stream>>>(keys, ui, labels, cosf_, s1, s2, cnt, besti, out);
  k_hist_rank<<<NCHUNK, 256, 0, stream>>>(labels, lrank, hist);
  k_prefix   <<<16, 64, 0, stream>>>(hist, base, class_n);
  k_scatter  <<<B_N / 256, 256, 0, stream>>>(labels, lrank, base, scores, ui, lists_s, lists_u);
  k_weight   <<<B_N / 256, 256, 0, stream>>>(labels, cosf_, s1, s2, cnt, out);
  k_replay   <<<250, 256, 0, stream>>>(ptn, lists_s, lists_u, class_n, labels, scores, ui, out);
  k_sel      <<<(ULB_N + 255) / 256, 256, 0, stream>>>(besti, labels, out);
}

// Round 3
// 187.287 us; speedup vs baseline: 2.7224x; 1.6222x over previous
//
#include <hip/hip_runtime.h>
#include <cstdint>
#include <cstddef>

#define B_N   32768
#define C_N   1000
#define C_PAD 1024
#define D_N   256
#define K_N   16
#define ULB_N 50000
#define NCHUNK 128           // B_N / 256
#define CAP_L 128            // per-class sorted-list capacity
#define KS_N  24             // 768 / 32 k-stages (split-bf16 concat K = 3*256)

// output layout (floats): label[B], weight[B], topN[C*K], fidx[C*K], selected[ULB]
#define OFF_L 0
#define OFF_W 32768
#define OFF_T 65536
#define OFF_F 81536
#define OFF_S 97536

typedef __attribute__((ext_vector_type(8))) short short8;
typedef __attribute__((ext_vector_type(4))) float f32x4;

__device__ __forceinline__ unsigned ordf(float f) {
  unsigned u = __float_as_uint(f);
  return (u & 0x80000000u) ? ~u : (u | 0x80000000u);
}
__device__ __forceinline__ float iordf(unsigned h) {
  unsigned u = (h & 0x80000000u) ? (h & 0x7FFFFFFFu) : ~h;
  return __uint_as_float(u);
}
__device__ __forceinline__ unsigned short f2bf(float f) {   // RNE fp32 -> bf16
  unsigned u = __float_as_uint(f);
  return (unsigned short)((u + 0x7FFFu + ((u >> 16) & 1u)) >> 16);
}
__device__ __forceinline__ float bf2f(unsigned short h) {
  return __uint_as_float(((unsigned)h) << 16);
}

__global__ void k_init(unsigned long long* keys, float* s1, float* s2,
                       int* cnt, int* besti) {
  int i = blockIdx.x * blockDim.x + threadIdx.x;
  if (i < B_N)  keys[i] = 0ull;
  if (i < C_PAD) { s1[i] = 0.f; s2[i] = 0.f; cnt[i] = 0; }
  if (i < ULB_N) besti[i] = -1;
}

// Normalize 16 rows, split to bf16 hi/lo, emit MFMA-fragment-packed K-concat tile.
// A' thirds: [hi | hi | lo]  (pairs with B' = [hi | lo | hi])
// Fragment layout: dst[mtL*1536 + ks*64 + l] = short8{ a(m = mt*16+(l&15), k = ks*32+(l>>4)*8+j) }
template<int ISB>
__global__ __launch_bounds__(256) void k_pack(const float* __restrict__ src,
                                              short8* __restrict__ dst,
                                              int mt0, int nreal) {
  __shared__ float s[16][260];     // padded: 260%32=4 -> only 2-way bank aliasing
  __shared__ float part[16][16];
  __shared__ float dv[16];
  const int t = threadIdx.x;
  const int mtL = blockIdx.x;
  const int r = t >> 4, c4 = (t & 15) * 4;
  const int grow = (mt0 + mtL) * 16 + r;
  #pragma unroll
  for (int i = 0; i < 4; ++i) {
    float4 v;
    if (grow < nreal) v = *reinterpret_cast<const float4*>(&src[(size_t)grow * D_N + c4 + 64 * i]);
    else { v.x = 0.f; v.y = 0.f; v.z = 0.f; v.w = 0.f; }
    s[r][c4 + 64 * i + 0] = v.x; s[r][c4 + 64 * i + 1] = v.y;
    s[r][c4 + 64 * i + 2] = v.z; s[r][c4 + 64 * i + 3] = v.w;
  }
  __syncthreads();
  {
    int c0 = t & 15;
    float ss = 0.f;
    #pragma unroll
    for (int j = 0; j < 16; ++j) { float x = s[r][c0 + 16 * j]; ss += x * x; }
    part[r][c0] = ss;
  }
  __syncthreads();
  if (t < 16) {
    float ss = 0.f;
    #pragma unroll
    for (int j = 0; j < 16; ++j) ss += part[t][j];
    dv[t] = 1.0f / fmaxf(sqrtf(ss), 1e-8f);
  }
  __syncthreads();
  #pragma unroll
  for (int i = 0; i < 6; ++i) {
    int p = t + 256 * i;            // 1536 fragment slots per 16-row tile
    int ks = p >> 6, l = p & 63;
    int mr = l & 15, g = l >> 4;
    int kc = ks * 32 + g * 8;
    int t3 = kc >> 8, k0 = kc & 255;
    float di = dv[mr];
    short8 v;
    #pragma unroll
    for (int j = 0; j < 8; ++j) {
      float q = s[mr][k0 + j] * di;
      unsigned short hi = f2bf(q);
      bool wantlo = ISB ? (t3 == 1) : (t3 == 2);
      unsigned short e = wantlo ? f2bf(q - bf2f(hi)) : hi;
      v[j] = (short)e;
    }
    dst[(size_t)mtL * 1536 + p] = v;
  }
}

// Fragment-direct MFMA GEMM: 128x128 tile, 4 waves of 64x64 (4x4 frags of 16x16x32),
// K = 768 in 24 stages, register double-buffer, no LDS / no barriers.
// Fused per-row argmax via packed-key atomicMax.
__global__ __launch_bounds__(256) void k_mfma(const short8* __restrict__ Ap,
                                              const short8* __restrict__ Bp,
                                              unsigned long long* __restrict__ keys,
                                              int row0) {
  const int bid = blockIdx.x;
  const int byl = bid >> 3, bx = bid & 7;
  const int w = threadIdx.x >> 6, l = threadIdx.x & 63;
  const int wm = (w & 1) * 64, wn = (w >> 1) * 64;
  const short8* a0 = Ap + (size_t)(byl * 8 + (wm >> 4)) * 1536 + l;
  const short8* b0 = Bp + (size_t)(bx * 8 + (wn >> 4)) * 1536 + l;

  f32x4 acc[4][4];
  #pragma unroll
  for (int i = 0; i < 4; ++i)
    #pragma unroll
    for (int j = 0; j < 4; ++j) { acc[i][j][0] = 0.f; acc[i][j][1] = 0.f; acc[i][j][2] = 0.f; acc[i][j][3] = 0.f; }

  short8 fA[4], fB[4], gA[4], gB[4];
#define LDF(d, b, ks) { d[0] = (b)[(ks)*64]; d[1] = (b)[(ks)*64 + 1536]; \
                        d[2] = (b)[(ks)*64 + 3072]; d[3] = (b)[(ks)*64 + 4608]; }
  LDF(fA, a0, 0) LDF(fB, b0, 0)
  for (int ks = 0; ks < KS_N; ks += 2) {
    LDF(gA, a0, ks + 1) LDF(gB, b0, ks + 1)
    #pragma unroll
    for (int mi = 0; mi < 4; ++mi)
      #pragma unroll
      for (int nj = 0; nj < 4; ++nj)
        acc[mi][nj] = __builtin_amdgcn_mfma_f32_16x16x32_bf16(fA[mi], fB[nj], acc[mi][nj], 0, 0, 0);
    if (ks + 2 < KS_N) { LDF(fA, a0, ks + 2) LDF(fB, b0, ks + 2) }
    #pragma unroll
    for (int mi = 0; mi < 4; ++mi)
      #pragma unroll
      for (int nj = 0; nj < 4; ++nj)
        acc[mi][nj] = __builtin_amdgcn_mfma_f32_16x16x32_bf16(gA[mi], gB[nj], acc[mi][nj], 0, 0, 0);
  }
#undef LDF

  // C/D layout: col = lane&15, row = (lane>>4)*4 + reg  [m89-verified]
  const int cb = bx * 128 + wn + (l & 15);
  #pragma unroll
  for (int mi = 0; mi < 4; ++mi) {
    #pragma unroll
    for (int r = 0; r < 4; ++r) {
      float bv = -INFINITY; int bc = 0x7FFFFFFF;
      #pragma unroll
      for (int nj = 0; nj < 4; ++nj) {
        int c = cb + nj * 16;
        float v = acc[mi][nj][r];
        if (c < C_N && v > bv) { bv = v; bc = c; }
      }
      #pragma unroll
      for (int mk = 1; mk < 16; mk <<= 1) {   // reduce the 16 lanes sharing (l>>4)
        float ov = __shfl_xor(bv, mk, 64);
        int oc = __shfl_xor(bc, mk, 64);
        if (ov > bv || (ov == bv && oc < bc)) { bv = ov; bc = oc; }
      }
      if ((l & 15) == 0) {
        unsigned long long kk =
            (((unsigned long long)ordf(bv)) << 32) |
            (unsigned long long)(0xFFFFFFFFu - (unsigned)bc);
        atomicMax(&keys[row0 + byl * 128 + wm + mi * 16 + (l >> 4) * 4 + r], kk);
      }
    }
  }
}

// row softmax max = 1/sum(exp(x - max))
__global__ __launch_bounds__(256) void k_scores(const float* __restrict__ pred,
                                                float* __restrict__ scores) {
  __shared__ float red[8];
  int r = blockIdx.x, t = threadIdx.x;
  const float* row = pred + (size_t)r * C_N;
  float x0 = row[t];
  float x1 = row[256 + t];
  float x2 = row[512 + t];
  bool v3 = (768 + t) < C_N;
  float x3 = v3 ? row[768 + t] : -INFINITY;
  float m = fmaxf(fmaxf(x0, x1), fmaxf(x2, x3));
  #pragma unroll
  for (int mk = 1; mk < 64; mk <<= 1) m = fmaxf(m, __shfl_xor(m, mk, 64));
  int wid = t >> 6, lane = t & 63;
  if (lane == 0) red[wid] = m;
  __syncthreads();
  m = fmaxf(fmaxf(red[0], red[1]), fmaxf(red[2], red[3]));
  float s = expf(x0 - m) + expf(x1 - m) + expf(x2 - m) + (v3 ? expf(x3 - m) : 0.f);
  #pragma unroll
  for (int mk = 1; mk < 64; mk <<= 1) s += __shfl_xor(s, mk, 64);
  __syncthreads();
  if (lane == 0) red[4 + wid] = s;
  __syncthreads();
  if (t == 0) {
    float S = ((red[4] + red[5]) + red[6]) + red[7];
    scores[r] = 1.0f / S;
  }
}

__global__ void k_post(const unsigned long long* __restrict__ keys, const int* __restrict__ ui,
                       int* __restrict__ labels, float* __restrict__ cosf_,
                       float* __restrict__ s1, float* __restrict__ s2, int* __restrict__ cnt,
                       int* __restrict__ besti, float* __restrict__ out) {
  int b = blockIdx.x * blockDim.x + threadIdx.x;
  if (b >= B_N) return;
  unsigned long long k = keys[b];
  int c = (int)(0xFFFFFFFFu - (unsigned)k);
  float f = iordf((unsigned)(k >> 32));
  labels[b] = c;
  cosf_[b] = f;
  out[OFF_L + b] = (float)c;
  atomicAdd(&s1[c], f);
  atomicAdd(&s2[c], f * f);
  atomicAdd(&cnt[c], 1);
  atomicMax(&besti[ui[b]], b);   // last-write-wins => largest sample index
}

// per-chunk class histogram + within-chunk stable rank (chunk = 256 samples)
__global__ __launch_bounds__(256) void k_hist_rank(const int* __restrict__ labels,
                                                   unsigned short* __restrict__ lrank,
                                                   unsigned short* __restrict__ hist) {
  __shared__ int lab[256];
  __shared__ unsigned histl[C_PAD];
  int chunk = blockIdx.x, t = threadIdx.x;
  int b = chunk * 256 + t;
  #pragma unroll
  for (int r = 0; r < 4; ++r) histl[t + 256 * r] = 0;
  int c = labels[b];
  lab[t] = c;
  __syncthreads();
  atomicAdd(&histl[c], 1u);
  unsigned rk = 0;
  for (int j = 0; j < t; ++j) rk += (lab[j] == c);
  lrank[b] = (unsigned short)rk;
  __syncthreads();
  #pragma unroll
  for (int r = 0; r < 4; ++r)
    hist[chunk * C_PAD + t + 256 * r] = (unsigned short)histl[t + 256 * r];
}

// per-class exclusive prefix over chunks; also total count per class
__global__ void k_prefix(const unsigned short* __restrict__ hist,
                         unsigned short* __restrict__ base,
                         int* __restrict__ class_n) {
  int c = blockIdx.x * 64 + threadIdx.x;   // 16 blocks x 64
  unsigned run = 0;
  for (int t = 0; t < NCHUNK; ++t) {
    unsigned h = hist[t * C_PAD + c];
    base[t * C_PAD + c] = (unsigned short)run;
    run += h;
  }
  class_n[c] = (int)run;
}

// merged: scatter score/ui into pre-sorted per-class lists + weight computation
__global__ __launch_bounds__(256) void k_sw(const int* __restrict__ labels,
                                            const unsigned short* __restrict__ lrank,
                                            const unsigned short* __restrict__ base,
                                            const float* __restrict__ scores,
                                            const int* __restrict__ ui,
                                            const float* __restrict__ cosf_,
                                            const float* __restrict__ s1,
                                            const float* __restrict__ s2,
                                            const int* __restrict__ cnt,
                                            float* __restrict__ lists_s,
                                            int* __restrict__ lists_u,
                                            float* __restrict__ out) {
  int b = blockIdx.x * blockDim.x + threadIdx.x;
  if (b >= B_N) return;
  int c = labels[b];
  int chunk = b >> 8;
  int pos = (int)base[chunk * C_PAD + c] + (int)lrank[b];
  if (pos < CAP_L) {
    lists_s[c * CAP_L + pos] = scores[b];
    lists_u[c * CAP_L + pos] = ui[b];
  }
  float n = (float)cnt[c];
  float m = s1[c] / fmaxf(n, 1.0f);
  float var = (s2[c] - n * m * m) / fmaxf(n - 1.0f, 1.0f);
  float sd = sqrtf(fmaxf(var, 0.0f) + 1e-12f);
  float cf = cosf_[b];
  float wgt = 1.0f;
  if (cf < m) {
    float z = (cf - m) / sd;
    const float inv = 0.3989422804014327f;
    wgt = expf(-0.5f * (z * z)) * inv / sd;
  }
  out[OFF_W + b] = wgt;
}

// one wave per class: parallel 64-wide gather of the pre-sorted list,
// serial top-16 replay via shfl broadcast (all lanes replicate state).
__global__ __launch_bounds__(256) void k_replay(const float* __restrict__ ptn,
                                                const float* __restrict__ lists_s,
                                                const int* __restrict__ lists_u,
                                                const int* __restrict__ class_n,
                                                const int* __restrict__ labels,
                                                const float* __restrict__ scores,
                                                const int* __restrict__ ui,
                                                float* __restrict__ out) {
  int c = blockIdx.x * 4 + (threadIdx.x >> 6);
  int lane = threadIdx.x & 63;
  if (c >= C_N) return;

  float tv[K_N]; int fi[K_N];
  #pragma unroll
  for (int j = 0; j < K_N; ++j) { tv[j] = ptn[c * K_N + j]; fi[j] = -1; }

  auto ins = [&](float s, int u) {
    float mv = tv[0]; int mi = 0;
    #pragma unroll
    for (int j = 1; j < K_N; ++j) { if (tv[j] < mv) { mv = tv[j]; mi = j; } }  // first-min
    if (s > mv) {
      #pragma unroll
      for (int j = 0; j < K_N; ++j) { if (j == mi) { tv[j] = s; fi[j] = u; } }
    }
  };

  int n = class_n[c];
  if (n <= CAP_L) {
    for (int t0 = 0; t0 < n; t0 += 64) {
      float s = 0.f; int u = 0;
      int idx = t0 + lane;
      if (idx < n) { s = lists_s[c * CAP_L + idx]; u = lists_u[c * CAP_L + idx]; }
      int lim = min(64, n - t0);
      for (int t = 0; t < lim; ++t) {
        float ss = __shfl(s, t, 64);
        int uu = __shfl(u, t, 64);
        ins(ss, uu);
      }
    }
  } else {
    // cooperative fallback (practically unreachable): scan all samples in order
    for (int t0 = 0; t0 < B_N; t0 += 64) {
      int lb = labels[t0 + lane];
      unsigned long long match = __ballot(lb == c);
      while (match) {
        int t = __ffsll((long long)match) - 1;
        match &= match - 1;
        int b = t0 + t;
        ins(scores[b], ui[b]);
      }
    }
  }

  if (lane == 0) {
    #pragma unroll
    for (int j = 0; j < K_N; ++j) {
      out[OFF_T + c * K_N + j] = tv[j];
      out[OFF_F + c * K_N + j] = (float)fi[j];
    }
  }
}

__global__ void k_sel(const int* __restrict__ besti, const int* __restrict__ labels,
                      float* __restrict__ out) {
  int p = blockIdx.x * blockDim.x + threadIdx.x;
  if (p >= ULB_N) return;
  int bi = besti[p];
  out[OFF_S + p] = (bi < 0) ? -1.0f : (float)labels[bi];
}

extern "C" void kernel_launch(void* const* d_in, const int* in_sizes, int n_in,
                              void* d_out, int out_size, void* d_ws, size_t ws_size,
                              hipStream_t stream) {
  const float* feat = (const float*)d_in[0];
  const float* pred = (const float*)d_in[1];
  const float* cent = (const float*)d_in[2];
  const float* ptn  = (const float*)d_in[3];
  const int*   ui   = (const int*)d_in[4];
  float* out = (float*)d_out;
  char* ws = (char*)d_ws;

  size_t o = 0;
  auto alloc = [&](size_t bytes) { void* p = ws + o; o += (bytes + 255) & ~size_t(255); return p; };
  short8* Bp                = (short8*)alloc(64 * 1536 * 16);        // 1.57 MB packed B'
  unsigned long long* keys  = (unsigned long long*)alloc(B_N * 8);
  int*   labels             = (int*)  alloc(B_N * 4);
  float* scores             = (float*)alloc(B_N * 4);
  float* cosf_              = (float*)alloc(B_N * 4);
  float* s1                 = (float*)alloc(C_PAD * 4);
  float* s2                 = (float*)alloc(C_PAD * 4);
  int*   cnt                = (int*)  alloc(C_PAD * 4);
  int*   besti              = (int*)  alloc(ULB_N * 4);
  unsigned short* lrank     = (unsigned short*)alloc(B_N * 2);
  unsigned short* hist      = (unsigned short*)alloc(NCHUNK * C_PAD * 2);
  unsigned short* base      = (unsigned short*)alloc(NCHUNK * C_PAD * 2);
  int*   class_n            = (int*)  alloc(C_PAD * 4);
  float* lists_s            = (float*)alloc(C_N * CAP_L * 4);
  int*   lists_u            = (int*)  alloc(C_N * CAP_L * 4);

  // A' chunk region: 196608 B per 128-row group (8 m-tiles x 1536 frags x 16 B)
  size_t avail = (ws_size > o) ? ws_size - o : 0;
  int g128 = (int)(avail / 196608ull);
  if (g128 < 1) g128 = 1;
  if (g128 > 256) g128 = 256;
  short8* Achunk = (short8*)(ws + o);

  k_init     <<<196, 256, 0, stream>>>(keys, s1, s2, cnt, besti);
  k_pack<1>  <<<64, 256, 0, stream>>>(cent, Bp, 0, C_N);
  for (int c0 = 0; c0 < 256; c0 += g128) {
    int g = (g128 < 256 - c0) ? g128 : (256 - c0);
    k_pack<0><<<g * 8, 256, 0, stream>>>(feat, Achunk, c0 * 8, B_N);
    k_mfma   <<<g * 8, 256, 0, stream>>>(Achunk, Bp, keys, c0 * 128);
  }
  k_scores   <<<B_N, 256, 0, stream>>>(pred, scores);
  k_post     <<<B_N / 256, 256, 0, stream>>>(keys, ui, labels, cosf_, s1, s2, cnt, besti, out);
  k_hist_rank<<<NCHUNK, 256, 0, stream>>>(labels, lrank, hist);
  k_prefix   <<<16, 64, 0, stream>>>(hist, base, class_n);
  k_sw       <<<B_N / 256, 256, 0, stream>>>(labels, lrank, base, scores, ui, cosf_, s1, s2, cnt, lists_s, lists_u, out);
  k_replay   <<<250, 256, 0, stream>>>(ptn, lists_s, lists_u, class_n, labels, scores, ui, out);
  k_sel      <<<(ULB_N + 255) / 256, 256, 0, stream>>>(besti, labels, out);
}